// Round 13
// baseline (188.036 us; speedup 1.0000x reference)
//
#include <hip/hip_runtime.h>
#include <math.h>

// Problem constants
#define NB 2
#define HIMG 96
#define HO 65
#define NCROPS (NB*HO*HO)   // 8450
#define NBLK 384            // grid: <= 2 blocks/CU capacity -> all co-resident

// pool1: [cls3=(img,o1,o2)][16ch][46][46]
#define P1_PLANE (46*46)          // 2116
#define P1_SIZE (8*16*P1_PLANE)   // 270848
// pool2: [cls5=(img,o1,o2,p1,p2)][32ch][22][22] f32
#define P2_PLANE (22*22)          // 484
#define P2_SIZE (32*32*P2_PLANE)  // 495616
// wBt: fragment-blocked NATIVE-K weights [nf 8][g 144][lm 16][8] bf16
#define WBT_SIZE (8*144*16*8)     // 147456

typedef __attribute__((ext_vector_type(8))) short bf16x8;
typedef __attribute__((ext_vector_type(4))) float f32x4;
typedef __attribute__((ext_vector_type(4), aligned(4))) float f32x4u;  // 4B-aligned vec load

__device__ __forceinline__ unsigned int f2bf(float x) {
    unsigned int u = __builtin_bit_cast(unsigned int, x);
    return (u + 0x7fffu + ((u >> 16) & 1u)) >> 16;
}
__device__ __forceinline__ unsigned int cvtpk(float lo, float hi) {
    unsigned int r;
    asm("v_cvt_pk_bf16_f32 %0, %1, %2" : "=v"(r) : "v"(lo), "v"(hi));
    return r;
}

// Device-scope arrival barrier: monotonic counter, per-phase target.
// All NBLK blocks are co-resident (2 blocks/CU capacity), so progress is
// guaranteed. Intermediates are replay-invariant, so stale-L1 reads after
// release are benign; the counter itself uses L2-coherent atomics.
__device__ __forceinline__ void gbar(unsigned* cnt, unsigned target) {
    __threadfence();          // drain this thread's global stores (device scope)
    __syncthreads();          // whole block done + fenced
    if (threadIdx.x == 0) {
        atomicAdd(cnt, 1u);
        while (atomicAdd(cnt, 0u) < target) __builtin_amdgcn_s_sleep(8);
    }
    __syncthreads();
}

// Single fused kernel: 384 blocks x 512 threads.
// Phase 1: conv1+pool1, wBt build, heatmap zero.   gbar
// Phase 2: conv2+ReLU+pool2 (LDS strip, 2 outputs/thread).   gbar
// Phase 3: FC1 MFMA GEMM + FC2 + sigmoid + scatter (578 tiles, grid-stride).
__global__ __launch_bounds__(512, 4) void k_all(
    const float* __restrict__ x,     const float* __restrict__ w1,
    const float* __restrict__ b1,    const float* __restrict__ w2,
    const float* __restrict__ b2,    const float* __restrict__ fc1_w,
    const float* __restrict__ fc1_b, const float* __restrict__ fc2_w,
    const float* __restrict__ fc2_b, float* __restrict__ pool1,
    float* __restrict__ pool2,       unsigned short* __restrict__ wBt,
    unsigned* __restrict__ cnt,      float* __restrict__ out)
{
    __shared__ __align__(16) union Sh {
        float sc[23][45];             // phase 2 conv strip (4.1 KB)
        unsigned short a[16][1160];   // phase 3 A-panel (36.3 KB)
        float h[16][132];             // phase 3 epilogue overlay
    } sh;

    int tid = threadIdx.x, b = blockIdx.x;

    // ================= Phase 1 =================
    for (int u = b; u < 337; u += NBLK) {
        int g = u * 512 + tid;
        if (g < 135424) {
            int pg = g % 23;
            int t  = g / 23;
            int py = t % 46;  t /= 46;
            int ch = t % 16;  t /= 16;                    // t = cls3
            int o2 = t & 1, o1 = (t >> 1) & 1, img = t >> 2;
            const float* xim = x + img * (HIMG * HIMG);

            int rbase = 2 * py + o1;
            int cb = 4 * pg + o2;
            bool cshift = (cb == 89);          // only (pg==22, o2==1) overflows
            if (cshift) cb = 88;
            float a[6][8];
            #pragma unroll
            for (int i = 0; i < 6; ++i) {
                int r = rbase + i; if (r > 95) r = 95;    // row clamp
                const float* rp = xim + r * 96 + cb;
                f32x4u lo = *(const f32x4u*)rp;
                f32x4u hi = *(const f32x4u*)(rp + 4);
                a[i][0] = lo.x; a[i][1] = lo.y; a[i][2] = lo.z; a[i][3] = lo.w;
                a[i][4] = hi.x; a[i][5] = hi.y; a[i][6] = hi.z; a[i][7] = hi.w;
            }
            if (cshift) {
                #pragma unroll
                for (int i = 0; i < 6; ++i)
                    #pragma unroll
                    for (int j = 0; j < 7; ++j) a[i][j] = a[i][j + 1];
            }
            const float* wc = w1 + ch * 25;
            float w[25];
            #pragma unroll
            for (int u2 = 0; u2 < 25; ++u2) w[u2] = wc[u2];
            float bias = b1[ch];

            float out0 = 0.f, out1 = 0.f;   // relu'd values >= 0
            #pragma unroll
            for (int dy = 0; dy < 2; ++dy)
                #pragma unroll
                for (int dx = 0; dx < 2; ++dx) {
                    float s0 = bias, s1 = bias;
                    #pragma unroll
                    for (int ky = 0; ky < 5; ++ky)
                        #pragma unroll
                        for (int kx = 0; kx < 5; ++kx) {
                            float wv = w[ky * 5 + kx];
                            s0 += a[dy + ky][dx + kx] * wv;
                            s1 += a[dy + ky][2 + dx + kx] * wv;
                        }
                    out0 = fmaxf(out0, s0);
                    out1 = fmaxf(out1, s1);
                }
            int base = ((t * 16 + ch) * 46 + py) * 46 + 2 * pg;
            float2 v; v.x = out0; v.y = out1;
            *(float2*)&pool1[base] = v;
        } else if (g < 153856) {
            int g2 = g - 135424;                  // < 18432, one 16B chunk
            int lm = g2 & 15;
            int gg = (g2 >> 4) % 144;
            int nf = g2 / 2304;
            int n  = nf * 16 + lm;
            const float* src = fc1_w + n * 1152 + gg * 8;
            f32x4u s0 = *(const f32x4u*)src;
            f32x4u s1 = *(const f32x4u*)(src + 4);
            uint4 v;
            v.x = f2bf(s0.x) | (f2bf(s0.y) << 16);
            v.y = f2bf(s0.z) | (f2bf(s0.w) << 16);
            v.z = f2bf(s1.x) | (f2bf(s1.y) << 16);
            v.w = f2bf(s1.z) | (f2bf(s1.w) << 16);
            ((uint4*)wBt)[g2] = v;
        } else if (g < 172288) {
            out[g - 153856] = 0.f;
        }
    }

    gbar(cnt, NBLK);

    // ================= Phase 2 =================
    for (int u = b; u < 512; u += NBLK) {
        int h = u & 1, oc = (u >> 1) & 31, cls3 = u >> 6;
        const float* p1base = pool1 + cls3 * 16 * P1_PLANE;
        const float* ww = w2 + oc * 144;        // block-uniform -> scalarized
        float bias = b2[oc];

        if (tid < 506) {
            int rl = tid / 22, og2 = tid - rl * 22;
            int oy = h * 22 + rl;
            if (oy < 44) {
                int ox0 = og2 * 2;
                const float* p1 = p1base + oy * 46 + ox0;
                float s0 = bias, s1 = bias;
                for (int ic = 0; ic < 16; ++ic) {
                    const float* pp = p1 + ic * P1_PLANE;
                    const float* wk = ww + ic * 9;
                    #pragma unroll
                    for (int ky = 0; ky < 3; ++ky) {
                        f32x4u lo = *(const f32x4u*)(pp + ky * 46);
                        float w0 = wk[ky * 3], w1v = wk[ky * 3 + 1], w2v = wk[ky * 3 + 2];
                        s0 += lo.x * w0 + lo.y * w1v + lo.z * w2v;
                        s1 += lo.y * w0 + lo.z * w1v + lo.w * w2v;
                    }
                }
                sh.sc[rl][ox0]     = fmaxf(s0, 0.f);
                sh.sc[rl][ox0 + 1] = fmaxf(s1, 0.f);
            }
        }
        __syncthreads();

        #pragma unroll
        for (int q2 = 0; q2 < 2; ++q2) {
            int p = tid + 512 * q2;
            if (p < 968) {
                int cls = p / 242;                  // (p1,p2)
                int cell = p - cls * 242;
                int eyl = cell / 22, ex = cell - eyl * 22;
                int ey = h * 11 + eyl;
                int p1v = cls >> 1, p2v = cls & 1;
                int r0 = 2 * ey + p1v, r1 = r0 + 1;
                if (r0 > 43) r0 = 43; if (r1 > 43) r1 = 43;
                int c0 = 2 * ex + p2v, c1 = c0 + 1;
                if (c0 > 43) c0 = 43; if (c1 > 43) c1 = 43;
                int rb = h * 22;
                float v = fmaxf(fmaxf(sh.sc[r0 - rb][c0], sh.sc[r0 - rb][c1]),
                                fmaxf(sh.sc[r1 - rb][c0], sh.sc[r1 - rb][c1]));
                pool2[((unsigned)((cls3 * 4 + cls) * 32 + oc)) * P2_PLANE + ey * 22 + ex] = v;
            }
        }
        __syncthreads();   // sc reads done before next unit's writes
    }

    gbar(cnt, 2 * NBLK);

    // ================= Phase 3 =================
    {
        int lane = tid & 63, wid = tid >> 6;
        int nsl = wid & 3, kh = wid >> 2;
        int lm = lane & 15, lg = lane >> 4;
        const unsigned short* bp0 = wBt + (nsl * 2) * 18432 + kh * 9216 + lg * 128 + lm * 8;
        const unsigned short* bp1 = bp0 + 18432;
        const unsigned short* ap  = &sh.a[lm][kh * 576 + lg * 8];

        for (int tile = b; tile < 578; tile += NBLK) {
            int m0 = tile * 16;

            // ---- Stage A: thread = (m = tid&15, ch = tid>>4) packs its
            // channel's 6x6 window into native k = ch*36 + mm*6 + nn.
            {
                int m = m0 + (tid & 15);
                int ch = tid >> 4;
                int cls5 = m / 289, r = m - cls5 * 289;
                int c = r / 17, d = r - c * 17;
                const float* abase = pool2 + cls5 * (32 * P2_PLANE) + ch * P2_PLANE + c * 22 + d;
                unsigned int arr[18];
                #pragma unroll
                for (int mm = 0; mm < 6; ++mm) {
                    f32x4u lo = *(const f32x4u*)(abase + mm * 22);
                    f32x4u hi = *(const f32x4u*)(abase + mm * 22 + 4);
                    arr[mm * 3 + 0] = cvtpk(lo.x, lo.y);
                    arr[mm * 3 + 1] = cvtpk(lo.z, lo.w);
                    arr[mm * 3 + 2] = cvtpk(hi.x, hi.y);
                }
                uint2* dst = (uint2*)&sh.a[tid & 15][ch * 36];
                #pragma unroll
                for (int q = 0; q < 9; ++q) {
                    uint2 w; w.x = arr[2 * q]; w.y = arr[2 * q + 1];
                    dst[q] = w;
                }
            }

            f32x4 acc0 = {0.f,0.f,0.f,0.f}, acc1 = {0.f,0.f,0.f,0.f};

            __syncthreads();

            #pragma unroll 6
            for (int kl = 0; kl < 18; ++kl) {
                bf16x8 a  = *(const bf16x8*)(ap + kl * 32);
                bf16x8 b0 = *(const bf16x8*)(bp0 + kl * 512);
                bf16x8 b1 = *(const bf16x8*)(bp1 + kl * 512);
                acc0 = __builtin_amdgcn_mfma_f32_16x16x32_bf16(a, b0, acc0, 0, 0, 0);
                acc1 = __builtin_amdgcn_mfma_f32_16x16x32_bf16(a, b1, acc1, 0, 0, 0);
            }

            __syncthreads();   // all sh.a reads complete before H overlay

            int col = nsl * 32 + lm;
            if (kh == 0) {
                #pragma unroll
                for (int r = 0; r < 4; ++r) {
                    sh.h[lg * 4 + r][col]      = acc0[r];
                    sh.h[lg * 4 + r][col + 16] = acc1[r];
                }
            }
            __syncthreads();
            if (kh == 1) {
                #pragma unroll
                for (int r = 0; r < 4; ++r) {
                    sh.h[lg * 4 + r][col]      += acc0[r];
                    sh.h[lg * 4 + r][col + 16] += acc1[r];
                }
            }
            __syncthreads();

            // FC2: 512 thr = 16 crops x 32 parts, 4 elems each.
            int crop_l = tid >> 5, part = tid & 31;
            float4 hv = *(const float4*)&sh.h[crop_l][part * 4];
            float4 fb = *(const float4*)&fc1_b[part * 4];
            float4 wv = *(const float4*)&fc2_w[part * 4];
            float s = fmaxf(hv.x + fb.x, 0.f) * wv.x
                    + fmaxf(hv.y + fb.y, 0.f) * wv.y
                    + fmaxf(hv.z + fb.z, 0.f) * wv.z
                    + fmaxf(hv.w + fb.w, 0.f) * wv.w;
            s += __shfl_down(s, 16, 32);
            s += __shfl_down(s, 8, 32);
            s += __shfl_down(s, 4, 32);
            s += __shfl_down(s, 2, 32);
            s += __shfl_down(s, 1, 32);
            if (part == 0) {
                int m = m0 + crop_l;                 // < 9248 always
                int cls5 = m / 289, r2 = m - cls5 * 289;
                int c = r2 / 17, d = r2 - c * 17;
                int img = cls5 >> 4, o1 = (cls5 >> 3) & 1, o2 = (cls5 >> 2) & 1;
                int p1 = (cls5 >> 1) & 1, p2 = cls5 & 1;
                int i = 4 * c + 2 * p1 + o1;
                int j = 4 * d + 2 * p2 + o2;
                if (i <= 64 && j <= 64) {
                    float q = 1.f / (1.f + expf(-(s + fc2_b[0])));
                    out[img * (HIMG * HIMG) + (16 + i) * HIMG + (16 + j)] = q;
                }
            }
            __syncthreads();   // sh.h reads done before next tile's sh.a writes
        }
    }
}

extern "C" void kernel_launch(void* const* d_in, const int* in_sizes, int n_in,
                              void* d_out, int out_size, void* d_ws, size_t ws_size,
                              hipStream_t stream) {
    const float* x     = (const float*)d_in[0];
    const float* w1    = (const float*)d_in[1];
    const float* b1    = (const float*)d_in[2];
    const float* w2    = (const float*)d_in[3];
    const float* b2    = (const float*)d_in[4];
    const float* fc1_w = (const float*)d_in[5];
    const float* fc1_b = (const float*)d_in[6];
    const float* fc2_w = (const float*)d_in[7];
    const float* fc2_b = (const float*)d_in[8];
    float* out = (float*)d_out;

    float* ws    = (float*)d_ws;
    float* pool1 = ws;                         // 270848 f32
    float* pool2 = pool1 + P1_SIZE;            // 495616 f32
    unsigned short* wBt = (unsigned short*)(pool2 + P2_SIZE);  // 147456 bf16
    unsigned* cnt = (unsigned*)(wBt + WBT_SIZE);

    hipMemsetAsync(cnt, 0, sizeof(unsigned), stream);   // reset barrier counter
    k_all<<<NBLK, 512, 0, stream>>>(x, w1, b1, w2, b2, fc1_w, fc1_b, fc2_w, fc2_b,
                                    pool1, pool2, wBt, cnt, out);
}

// Round 14
// 32.132 us; speedup vs baseline: 5.8520x; 5.8520x over previous
//
#include <hip/hip_runtime.h>
#include <math.h>

// Problem constants
#define NB 2
#define HIMG 96
#define HO 65
#define NCROPS (NB*HO*HO)   // 8450

// pool1: [cls3=(img,o1,o2)][16ch][46][46]
#define P1_PLANE (46*46)          // 2116
#define P1_SIZE (8*16*P1_PLANE)   // 270848
// pool2: [cls5=(img,o1,o2,p1,p2)][32ch][22][22] f32
#define P2_PLANE (22*22)          // 484
#define P2_SIZE (32*32*P2_PLANE)  // 495616
// wBt: fragment-blocked NATIVE-K weights [nf 8][g 144][lm 16][8] bf16
#define WBT_SIZE (8*144*16*8)     // 147456

typedef __attribute__((ext_vector_type(8))) short bf16x8;
typedef __attribute__((ext_vector_type(4))) float f32x4;
typedef __attribute__((ext_vector_type(4), aligned(4))) float f32x4u;  // 4B-aligned vec load

__device__ __forceinline__ unsigned int f2bf(float x) {
    unsigned int u = __builtin_bit_cast(unsigned int, x);
    return (u + 0x7fffu + ((u >> 16) & 1u)) >> 16;
}
__device__ __forceinline__ unsigned int cvtpk(float lo, float hi) {
    unsigned int r;
    asm("v_cvt_pk_bf16_f32 %0, %1, %2" : "=v"(r) : "v"(lo), "v"(hi));
    return r;
}

// Merged front kernel:
//   blocks [0,640)   : conv1(5x5,1->16)+ReLU+2x2 maxpool at parity -> pool1.
//                      block = (combo = cls3*16+ch) * 5 + seg: (cls3,ch) is
//                      BLOCK-UNIFORM -> the 25 conv1 weights are scalar
//                      s_loads shared by the block (no per-thread VGPR loads).
//   blocks [640,712) : build wBt (native-K fragment-blocked bf16 fc1 weights)
//   blocks [712,784) : zero heatmap
__global__ void k_front(const float* __restrict__ x, const float* __restrict__ w1,
                        const float* __restrict__ b1, float* __restrict__ pool1,
                        const float* __restrict__ fc1_w, unsigned short* __restrict__ wBt,
                        float* __restrict__ out) {
    int b = blockIdx.x, tid = threadIdx.x;
    if (b >= 640) {
        if (b < 712) {
            int g2 = (b - 640) * 256 + tid;       // < 18432, one 16B chunk each
            int lm = g2 & 15;
            int gg = (g2 >> 4) % 144;
            int nf = g2 / 2304;
            int n  = nf * 16 + lm;
            const float* src = fc1_w + n * 1152 + gg * 8;   // 8 consecutive native k
            f32x4u s0 = *(const f32x4u*)src;
            f32x4u s1 = *(const f32x4u*)(src + 4);
            uint4 v;
            v.x = f2bf(s0.x) | (f2bf(s0.y) << 16);
            v.y = f2bf(s0.z) | (f2bf(s0.w) << 16);
            v.z = f2bf(s1.x) | (f2bf(s1.y) << 16);
            v.w = f2bf(s1.z) | (f2bf(s1.w) << 16);
            ((uint4*)wBt)[g2] = v;
        } else {
            out[(b - 712) * 256 + tid] = 0.f;
        }
        return;
    }
    // conv1: block-uniform (cls3, ch); thread-cell = (py, pg) covering 2 outputs
    int seg   = b % 5;
    int combo = b / 5;                    // cls3*16 + ch
    int ch    = combo & 15, cls3 = combo >> 4;
    int cell  = seg * 256 + tid;
    if (cell >= 1058) return;             // 46*23
    int py = cell / 23, pg = cell - py * 23;
    int o2 = cls3 & 1, o1 = (cls3 >> 1) & 1, img = cls3 >> 2;
    const float* xim = x + img * (HIMG * HIMG);

    const float* wc = w1 + ch * 25;       // uniform -> scalar loads
    float w[25];
    #pragma unroll
    for (int u = 0; u < 25; ++u) w[u] = wc[u];
    float bias = b1[ch];

    int rbase = 2 * py + o1;
    int cb = 4 * pg + o2;
    bool cshift = (cb == 89);             // only (pg==22, o2==1) overflows cols
    if (cshift) cb = 88;
    float a[6][8];
    #pragma unroll
    for (int i = 0; i < 6; ++i) {
        int r = rbase + i; if (r > 95) r = 95;        // row clamp (py=45,o1=1)
        const float* rp = xim + r * 96 + cb;
        f32x4u lo = *(const f32x4u*)rp;
        f32x4u hi = *(const f32x4u*)(rp + 4);
        a[i][0] = lo.x; a[i][1] = lo.y; a[i][2] = lo.z; a[i][3] = lo.w;
        a[i][4] = hi.x; a[i][5] = hi.y; a[i][6] = hi.z; a[i][7] = hi.w;
    }
    if (cshift) {
        // loaded cols 88..95; need cols min(89+j,95): shift left, keep last
        #pragma unroll
        for (int i = 0; i < 6; ++i)
            #pragma unroll
            for (int j = 0; j < 7; ++j) a[i][j] = a[i][j + 1];
    }

    float out0 = 0.f, out1 = 0.f;   // relu'd values >= 0
    #pragma unroll
    for (int dy = 0; dy < 2; ++dy)
        #pragma unroll
        for (int dx = 0; dx < 2; ++dx) {
            float s0 = bias, s1 = bias;
            #pragma unroll
            for (int ky = 0; ky < 5; ++ky)
                #pragma unroll
                for (int kx = 0; kx < 5; ++kx) {
                    float wv = w[ky * 5 + kx];
                    s0 += a[dy + ky][dx + kx] * wv;
                    s1 += a[dy + ky][2 + dx + kx] * wv;
                }
            out0 = fmaxf(out0, s0);
            out1 = fmaxf(out1, s1);
        }
    int base = (combo * 46 + py) * 46 + 2 * pg;
    float2 v; v.x = out0; v.y = out1;
    *(float2*)&pool1[base] = v;
}

// Fused conv2(3x3,16->32)+ReLU+pool2: block = (cls3, oc, row-half h).
// Conv rows loaded as two f32x4u (8 floats); weights block-uniform (scalar).
// Vector tails read <=2 floats past pool1 (into pool2 region of ws; unused).
__global__ __launch_bounds__(256) void k_convpool(const float* __restrict__ pool1,
                                                  const float* __restrict__ w2,
                                                  const float* __restrict__ b2,
                                                  float* __restrict__ pool2) {
    __shared__ float sc[23][45];
    int b = blockIdx.x;                     // < 512
    int h = b & 1, oc = (b >> 1) & 31, cls3 = b >> 6;
    int tid = threadIdx.x;
    const float* p1base = pool1 + cls3 * 16 * P1_PLANE;
    const float* ww = w2 + oc * 144;        // block-uniform -> scalarized
    float bias = b2[oc];

    if (tid < 253) {
        int rl = tid / 11, og = tid - rl * 11;
        int oy = h * 22 + rl;
        if (oy < 44) {
            int ox0 = og * 4;
            const float* p1 = p1base + oy * 46 + ox0;
            float s0 = bias, s1 = bias, s2 = bias, s3 = bias;
            for (int ic = 0; ic < 16; ++ic) {
                const float* pp = p1 + ic * P1_PLANE;
                const float* wk = ww + ic * 9;
                #pragma unroll
                for (int ky = 0; ky < 3; ++ky) {
                    const float* r = pp + ky * 46;
                    f32x4u lo = *(const f32x4u*)r;
                    f32x4u hi = *(const f32x4u*)(r + 4);
                    float w0 = wk[ky * 3], w1v = wk[ky * 3 + 1], w2v = wk[ky * 3 + 2];
                    s0 += lo.x * w0 + lo.y * w1v + lo.z * w2v;
                    s1 += lo.y * w0 + lo.z * w1v + lo.w * w2v;
                    s2 += lo.z * w0 + lo.w * w1v + hi.x * w2v;
                    s3 += lo.w * w0 + hi.x * w1v + hi.y * w2v;
                }
            }
            sc[rl][ox0]     = fmaxf(s0, 0.f);
            sc[rl][ox0 + 1] = fmaxf(s1, 0.f);
            sc[rl][ox0 + 2] = fmaxf(s2, 0.f);
            sc[rl][ox0 + 3] = fmaxf(s3, 0.f);
        }
    }
    __syncthreads();

    #pragma unroll
    for (int q2 = 0; q2 < 4; ++q2) {
        int p = tid + 256 * q2;
        if (p < 968) {
            int cls = p / 242;                  // (p1,p2)
            int cell = p - cls * 242;
            int eyl = cell / 22, ex = cell - eyl * 22;
            int ey = h * 11 + eyl;
            int p1v = cls >> 1, p2v = cls & 1;
            int r0 = 2 * ey + p1v, r1 = r0 + 1;
            if (r0 > 43) r0 = 43; if (r1 > 43) r1 = 43;
            int c0 = 2 * ex + p2v, c1 = c0 + 1;
            if (c0 > 43) c0 = 43; if (c1 > 43) c1 = 43;
            int rb = h * 22;
            float v = fmaxf(fmaxf(sc[r0 - rb][c0], sc[r0 - rb][c1]),
                            fmaxf(sc[r1 - rb][c0], sc[r1 - rb][c1]));
            pool2[((unsigned)((cls3 * 4 + cls) * 32 + oc)) * P2_PLANE + ey * 22 + ex] = v;
        }
    }
}

// FC GEMM: BM=16, native K=1152 (36 slices), 578 blocks x 512 thr
// (8 waves = 4 nsl x 2 kh). A staged once in LDS [16][1160] bf16 (36.3 KB,
// union'd with the epilogue H buffer -> 4 blocks/CU, all blocks resident).
__global__ __launch_bounds__(512, 4) void k_fc(const float* __restrict__ pool2,
                                               const unsigned short* __restrict__ wBt,
                                               const float* __restrict__ fc1_b,
                                               const float* __restrict__ fc2_w,
                                               const float* __restrict__ fc2_b,
                                               float* __restrict__ out) {
    __shared__ __align__(16) union ShMem {
        unsigned short a[16][1160];   // row stride 2320 B (16B-aligned; 2-way banks)
        float h[16][132];             // epilogue overlay (8.4 KB < 36.3 KB)
    } sh;

    int tid = threadIdx.x;
    int m0  = blockIdx.x * 16;

    // ---- Stage A: thread = (m = tid&15, ch = tid>>4) packs its channel's
    // 6x6 window into native k = ch*36 + mm*6 + nn (72 B contiguous).
    {
        int m = m0 + (tid & 15);
        int ch = tid >> 4;
        int cls5 = m / 289, r = m - cls5 * 289;
        int c = r / 17, d = r - c * 17;
        const float* abase = pool2 + cls5 * (32 * P2_PLANE) + ch * P2_PLANE + c * 22 + d;
        unsigned int arr[18];
        #pragma unroll
        for (int mm = 0; mm < 6; ++mm) {
            f32x4u lo = *(const f32x4u*)(abase + mm * 22);
            f32x4u hi = *(const f32x4u*)(abase + mm * 22 + 4);
            arr[mm * 3 + 0] = cvtpk(lo.x, lo.y);
            arr[mm * 3 + 1] = cvtpk(lo.z, lo.w);
            arr[mm * 3 + 2] = cvtpk(hi.x, hi.y);
        }
        uint2* dst = (uint2*)&sh.a[tid & 15][ch * 36];
        #pragma unroll
        for (int q = 0; q < 9; ++q) {
            uint2 w; w.x = arr[2 * q]; w.y = arr[2 * q + 1];
            dst[q] = w;
        }
    }

    int lane = tid & 63, wid = tid >> 6;
    int nsl = wid & 3, kh = wid >> 2;
    int lm = lane & 15, lg = lane >> 4;

    const unsigned short* bp0 = wBt + (nsl * 2) * 18432 + kh * 9216 + lg * 128 + lm * 8;
    const unsigned short* bp1 = bp0 + 18432;
    const unsigned short* ap  = &sh.a[lm][kh * 576 + lg * 8];

    f32x4 acc0 = {0.f,0.f,0.f,0.f}, acc1 = {0.f,0.f,0.f,0.f};

    __syncthreads();

    #pragma unroll 6
    for (int kl = 0; kl < 18; ++kl) {
        bf16x8 a  = *(const bf16x8*)(ap + kl * 32);
        bf16x8 b0 = *(const bf16x8*)(bp0 + kl * 512);
        bf16x8 b1 = *(const bf16x8*)(bp1 + kl * 512);
        acc0 = __builtin_amdgcn_mfma_f32_16x16x32_bf16(a, b0, acc0, 0, 0, 0);
        acc1 = __builtin_amdgcn_mfma_f32_16x16x32_bf16(a, b1, acc1, 0, 0, 0);
    }

    __syncthreads();   // all sa reads complete before H overlay

    int col = nsl * 32 + lm;
    if (kh == 0) {
        #pragma unroll
        for (int r = 0; r < 4; ++r) {
            sh.h[lg * 4 + r][col]      = acc0[r];
            sh.h[lg * 4 + r][col + 16] = acc1[r];
        }
    }
    __syncthreads();
    if (kh == 1) {
        #pragma unroll
        for (int r = 0; r < 4; ++r) {
            sh.h[lg * 4 + r][col]      += acc0[r];
            sh.h[lg * 4 + r][col + 16] += acc1[r];
        }
    }
    __syncthreads();

    // FC2: 512 thr = 16 crops x 32 parts, 4 elems each; reduce within 32 lanes.
    int crop_l = tid >> 5, part = tid & 31;
    float4 hv = *(const float4*)&sh.h[crop_l][part * 4];
    float4 fb = *(const float4*)&fc1_b[part * 4];
    float4 wv = *(const float4*)&fc2_w[part * 4];
    float s = fmaxf(hv.x + fb.x, 0.f) * wv.x
            + fmaxf(hv.y + fb.y, 0.f) * wv.y
            + fmaxf(hv.z + fb.z, 0.f) * wv.z
            + fmaxf(hv.w + fb.w, 0.f) * wv.w;
    s += __shfl_down(s, 16, 32);
    s += __shfl_down(s, 8, 32);
    s += __shfl_down(s, 4, 32);
    s += __shfl_down(s, 2, 32);
    s += __shfl_down(s, 1, 32);
    if (part == 0) {
        int m = m0 + crop_l;                 // < 9248 always
        int cls5 = m / 289, r2 = m - cls5 * 289;
        int c = r2 / 17, d = r2 - c * 17;
        int img = cls5 >> 4, o1 = (cls5 >> 3) & 1, o2 = (cls5 >> 2) & 1;
        int p1 = (cls5 >> 1) & 1, p2 = cls5 & 1;
        int i = 4 * c + 2 * p1 + o1;
        int j = 4 * d + 2 * p2 + o2;
        if (i <= 64 && j <= 64) {
            float q = 1.f / (1.f + expf(-(s + fc2_b[0])));
            out[img * (HIMG * HIMG) + (16 + i) * HIMG + (16 + j)] = q;
        }
    }
}

extern "C" void kernel_launch(void* const* d_in, const int* in_sizes, int n_in,
                              void* d_out, int out_size, void* d_ws, size_t ws_size,
                              hipStream_t stream) {
    const float* x     = (const float*)d_in[0];
    const float* w1    = (const float*)d_in[1];
    const float* b1    = (const float*)d_in[2];
    const float* w2    = (const float*)d_in[3];
    const float* b2    = (const float*)d_in[4];
    const float* fc1_w = (const float*)d_in[5];
    const float* fc1_b = (const float*)d_in[6];
    const float* fc2_w = (const float*)d_in[7];
    const float* fc2_b = (const float*)d_in[8];
    float* out = (float*)d_out;

    float* ws    = (float*)d_ws;
    float* pool1 = ws;                         // 270848 f32
    float* pool2 = pool1 + P1_SIZE;            // 495616 f32
    unsigned short* wBt = (unsigned short*)(pool2 + P2_SIZE);  // 147456 bf16

    k_front<<<784, 256, 0, stream>>>(x, w1, b1, pool1, fc1_w, wBt, out);
    k_convpool<<<512, 256, 0, stream>>>(pool1, w2, b2, pool2);
    k_fc<<<578, 512, 0, stream>>>(pool2, wBt, fc1_b, fc2_w, fc2_b, out);
}

// Round 15
// 29.438 us; speedup vs baseline: 6.3876x; 1.0915x over previous
//
#include <hip/hip_runtime.h>
#include <math.h>

// Problem constants
#define NB 2
#define HIMG 96
#define HO 65
#define NCROPS (NB*HO*HO)   // 8450

// pool1: [cls3=(img,o1,o2)][16ch][46][46]
#define P1_PLANE (46*46)          // 2116
#define P1_SIZE (8*16*P1_PLANE)   // 270848
// pool2: [cls5=(img,o1,o2,p1,p2)][32ch][22][22] f32
#define P2_PLANE (22*22)          // 484
#define P2_SIZE (32*32*P2_PLANE)  // 495616
// wBt: fragment-blocked NATIVE-K weights [nf 8][g 144][lm 16][8] bf16
#define WBT_SIZE (8*144*16*8)     // 147456

typedef __attribute__((ext_vector_type(8))) short bf16x8;
typedef __attribute__((ext_vector_type(4))) float f32x4;
typedef __attribute__((ext_vector_type(4), aligned(4))) float f32x4u;  // 4B-aligned vec load

__device__ __forceinline__ unsigned int f2bf(float x) {
    unsigned int u = __builtin_bit_cast(unsigned int, x);
    return (u + 0x7fffu + ((u >> 16) & 1u)) >> 16;
}
__device__ __forceinline__ unsigned int cvtpk(float lo, float hi) {
    unsigned int r;
    asm("v_cvt_pk_bf16_f32 %0, %1, %2" : "=v"(r) : "v"(lo), "v"(hi));
    return r;
}

// Merged front kernel:
//   blocks [0,640)   : conv1(5x5,1->16)+ReLU+2x2 maxpool at parity -> pool1.
//                      block = (combo = cls3*16+ch) * 5 + seg: (cls3,ch) is
//                      BLOCK-UNIFORM -> the 25 conv1 weights are scalar s_loads.
//   blocks [640,712) : build wBt (native-K fragment-blocked bf16 fc1 weights)
//   blocks [712,784) : zero heatmap
__global__ void k_front(const float* __restrict__ x, const float* __restrict__ w1,
                        const float* __restrict__ b1, float* __restrict__ pool1,
                        const float* __restrict__ fc1_w, unsigned short* __restrict__ wBt,
                        float* __restrict__ out) {
    int b = blockIdx.x, tid = threadIdx.x;
    if (b >= 640) {
        if (b < 712) {
            int g2 = (b - 640) * 256 + tid;       // < 18432, one 16B chunk each
            int lm = g2 & 15;
            int gg = (g2 >> 4) % 144;
            int nf = g2 / 2304;
            int n  = nf * 16 + lm;
            const float* src = fc1_w + n * 1152 + gg * 8;   // 8 consecutive native k
            f32x4u s0 = *(const f32x4u*)src;
            f32x4u s1 = *(const f32x4u*)(src + 4);
            uint4 v;
            v.x = f2bf(s0.x) | (f2bf(s0.y) << 16);
            v.y = f2bf(s0.z) | (f2bf(s0.w) << 16);
            v.z = f2bf(s1.x) | (f2bf(s1.y) << 16);
            v.w = f2bf(s1.z) | (f2bf(s1.w) << 16);
            ((uint4*)wBt)[g2] = v;
        } else {
            out[(b - 712) * 256 + tid] = 0.f;
        }
        return;
    }
    // conv1: block-uniform (cls3, ch); thread-cell = (py, pg) covering 2 outputs
    int seg   = b % 5;
    int combo = b / 5;                    // cls3*16 + ch
    int ch    = combo & 15, cls3 = combo >> 4;
    int cell  = seg * 256 + tid;
    if (cell >= 1058) return;             // 46*23
    int py = cell / 23, pg = cell - py * 23;
    int o2 = cls3 & 1, o1 = (cls3 >> 1) & 1, img = cls3 >> 2;
    const float* xim = x + img * (HIMG * HIMG);

    const float* wc = w1 + ch * 25;       // uniform -> scalar loads
    float w[25];
    #pragma unroll
    for (int u = 0; u < 25; ++u) w[u] = wc[u];
    float bias = b1[ch];

    int rbase = 2 * py + o1;
    int cb = 4 * pg + o2;
    bool cshift = (cb == 89);             // only (pg==22, o2==1) overflows cols
    if (cshift) cb = 88;
    float a[6][8];
    #pragma unroll
    for (int i = 0; i < 6; ++i) {
        int r = rbase + i; if (r > 95) r = 95;        // row clamp (py=45,o1=1)
        const float* rp = xim + r * 96 + cb;
        f32x4u lo = *(const f32x4u*)rp;
        f32x4u hi = *(const f32x4u*)(rp + 4);
        a[i][0] = lo.x; a[i][1] = lo.y; a[i][2] = lo.z; a[i][3] = lo.w;
        a[i][4] = hi.x; a[i][5] = hi.y; a[i][6] = hi.z; a[i][7] = hi.w;
    }
    if (cshift) {
        #pragma unroll
        for (int i = 0; i < 6; ++i)
            #pragma unroll
            for (int j = 0; j < 7; ++j) a[i][j] = a[i][j + 1];
    }

    float out0 = 0.f, out1 = 0.f;   // relu'd values >= 0
    #pragma unroll
    for (int dy = 0; dy < 2; ++dy)
        #pragma unroll
        for (int dx = 0; dx < 2; ++dx) {
            float s0 = bias, s1 = bias;
            #pragma unroll
            for (int ky = 0; ky < 5; ++ky)
                #pragma unroll
                for (int kx = 0; kx < 5; ++kx) {
                    float wv = w[ky * 5 + kx];
                    s0 += a[dy + ky][dx + kx] * wv;
                    s1 += a[dy + ky][2 + dx + kx] * wv;
                }
            out0 = fmaxf(out0, s0);
            out1 = fmaxf(out1, s1);
        }
    int base = (combo * 46 + py) * 46 + 2 * pg;
    float2 v; v.x = out0; v.y = out1;
    *(float2*)&pool1[base] = v;
}

// Fused conv2(3x3,16->32)+ReLU+pool2: block = (cls3, oc, row-half h).
// Conv rows loaded as two f32x4u (8 floats); weights block-uniform (scalar).
__global__ __launch_bounds__(256) void k_convpool(const float* __restrict__ pool1,
                                                  const float* __restrict__ w2,
                                                  const float* __restrict__ b2,
                                                  float* __restrict__ pool2) {
    __shared__ float sc[23][45];
    int b = blockIdx.x;                     // < 512
    int h = b & 1, oc = (b >> 1) & 31, cls3 = b >> 6;
    int tid = threadIdx.x;
    const float* p1base = pool1 + cls3 * 16 * P1_PLANE;
    const float* ww = w2 + oc * 144;        // block-uniform -> scalarized
    float bias = b2[oc];

    if (tid < 253) {
        int rl = tid / 11, og = tid - rl * 11;
        int oy = h * 22 + rl;
        if (oy < 44) {
            int ox0 = og * 4;
            const float* p1 = p1base + oy * 46 + ox0;
            float s0 = bias, s1 = bias, s2 = bias, s3 = bias;
            for (int ic = 0; ic < 16; ++ic) {
                const float* pp = p1 + ic * P1_PLANE;
                const float* wk = ww + ic * 9;
                #pragma unroll
                for (int ky = 0; ky < 3; ++ky) {
                    const float* r = pp + ky * 46;
                    f32x4u lo = *(const f32x4u*)r;
                    f32x4u hi = *(const f32x4u*)(r + 4);
                    float w0 = wk[ky * 3], w1v = wk[ky * 3 + 1], w2v = wk[ky * 3 + 2];
                    s0 += lo.x * w0 + lo.y * w1v + lo.z * w2v;
                    s1 += lo.y * w0 + lo.z * w1v + lo.w * w2v;
                    s2 += lo.z * w0 + lo.w * w1v + hi.x * w2v;
                    s3 += lo.w * w0 + hi.x * w1v + hi.y * w2v;
                }
            }
            sc[rl][ox0]     = fmaxf(s0, 0.f);
            sc[rl][ox0 + 1] = fmaxf(s1, 0.f);
            sc[rl][ox0 + 2] = fmaxf(s2, 0.f);
            sc[rl][ox0 + 3] = fmaxf(s3, 0.f);
        }
    }
    __syncthreads();

    #pragma unroll
    for (int q2 = 0; q2 < 4; ++q2) {
        int p = tid + 256 * q2;
        if (p < 968) {
            int cls = p / 242;                  // (p1,p2)
            int cell = p - cls * 242;
            int eyl = cell / 22, ex = cell - eyl * 22;
            int ey = h * 11 + eyl;
            int p1v = cls >> 1, p2v = cls & 1;
            int r0 = 2 * ey + p1v, r1 = r0 + 1;
            if (r0 > 43) r0 = 43; if (r1 > 43) r1 = 43;
            int c0 = 2 * ex + p2v, c1 = c0 + 1;
            if (c0 > 43) c0 = 43; if (c1 > 43) c1 = 43;
            int rb = h * 22;
            float v = fmaxf(fmaxf(sc[r0 - rb][c0], sc[r0 - rb][c1]),
                            fmaxf(sc[r1 - rb][c0], sc[r1 - rb][c1]));
            pool2[((unsigned)((cls3 * 4 + cls) * 32 + oc)) * P2_PLANE + ey * 22 + ex] = v;
        }
    }
}

// FC GEMM: BM=32, native K=1152 (36 slices), 289 blocks x 512 thr
// (8 waves = 4 nsl x 2 kh; each wave owns 2 M-fragments -> 4 MFMA/slice).
// A staged once in LDS [32][1160] bf16 (72.5 KB, union'd with H -> 2 blocks/CU,
// all 289 blocks resident). Halves per-output B traffic vs BM=16 (83 MB L2).
__global__ __launch_bounds__(512, 4) void k_fc(const float* __restrict__ pool2,
                                               const unsigned short* __restrict__ wBt,
                                               const float* __restrict__ fc1_b,
                                               const float* __restrict__ fc2_w,
                                               const float* __restrict__ fc2_b,
                                               float* __restrict__ out) {
    __shared__ __align__(16) union ShMem {
        unsigned short a[32][1160];   // row stride 2320 B (16B multiple)
        float h[32][132];             // epilogue overlay (16.9 KB < 72.5 KB)
    } sh;

    int tid = threadIdx.x;
    int m0  = blockIdx.x * 32;

    // ---- Stage A: thread = (m = tid&31, ch0 = tid>>5); packs channels ch0, ch0+16
    {
        int m = m0 + (tid & 31);
        int cls5 = m / 289, r = m - cls5 * 289;
        int c = r / 17, d = r - c * 17;
        const float* base0 = pool2 + cls5 * (32 * P2_PLANE) + c * 22 + d;
        #pragma unroll
        for (int cc = 0; cc < 2; ++cc) {
            int ch = (tid >> 5) + cc * 16;
            const float* abase = base0 + ch * P2_PLANE;
            unsigned int arr[18];
            #pragma unroll
            for (int mm = 0; mm < 6; ++mm) {
                f32x4u lo = *(const f32x4u*)(abase + mm * 22);
                f32x4u hi = *(const f32x4u*)(abase + mm * 22 + 4);
                arr[mm * 3 + 0] = cvtpk(lo.x, lo.y);
                arr[mm * 3 + 1] = cvtpk(lo.z, lo.w);
                arr[mm * 3 + 2] = cvtpk(hi.x, hi.y);
            }
            uint2* dst = (uint2*)&sh.a[tid & 31][ch * 36];
            #pragma unroll
            for (int q = 0; q < 9; ++q) {
                uint2 w; w.x = arr[2 * q]; w.y = arr[2 * q + 1];
                dst[q] = w;
            }
        }
    }

    int lane = tid & 63, wid = tid >> 6;
    int nsl = wid & 3, kh = wid >> 2;
    int lm = lane & 15, lg = lane >> 4;

    const unsigned short* bp0 = wBt + (nsl * 2) * 18432 + kh * 9216 + lg * 128 + lm * 8;
    const unsigned short* bp1 = bp0 + 18432;
    const unsigned short* ap0 = &sh.a[lm][kh * 576 + lg * 8];
    const unsigned short* ap1 = &sh.a[16 + lm][kh * 576 + lg * 8];

    f32x4 acc00 = {0.f,0.f,0.f,0.f}, acc01 = {0.f,0.f,0.f,0.f};
    f32x4 acc10 = {0.f,0.f,0.f,0.f}, acc11 = {0.f,0.f,0.f,0.f};

    __syncthreads();

    #pragma unroll 6
    for (int kl = 0; kl < 18; ++kl) {
        bf16x8 a0 = *(const bf16x8*)(ap0 + kl * 32);
        bf16x8 a1 = *(const bf16x8*)(ap1 + kl * 32);
        bf16x8 b0 = *(const bf16x8*)(bp0 + kl * 512);
        bf16x8 b1 = *(const bf16x8*)(bp1 + kl * 512);
        acc00 = __builtin_amdgcn_mfma_f32_16x16x32_bf16(a0, b0, acc00, 0, 0, 0);
        acc01 = __builtin_amdgcn_mfma_f32_16x16x32_bf16(a0, b1, acc01, 0, 0, 0);
        acc10 = __builtin_amdgcn_mfma_f32_16x16x32_bf16(a1, b0, acc10, 0, 0, 0);
        acc11 = __builtin_amdgcn_mfma_f32_16x16x32_bf16(a1, b1, acc11, 0, 0, 0);
    }

    __syncthreads();   // all sh.a reads complete before H overlay

    // Reduce kh halves. D layout: row (m) = lg*4+r, col (n) = lm.
    int col = nsl * 32 + lm;
    if (kh == 0) {
        #pragma unroll
        for (int r = 0; r < 4; ++r) {
            sh.h[lg * 4 + r][col]           = acc00[r];
            sh.h[lg * 4 + r][col + 16]      = acc01[r];
            sh.h[16 + lg * 4 + r][col]      = acc10[r];
            sh.h[16 + lg * 4 + r][col + 16] = acc11[r];
        }
    }
    __syncthreads();
    if (kh == 1) {
        #pragma unroll
        for (int r = 0; r < 4; ++r) {
            sh.h[lg * 4 + r][col]           += acc00[r];
            sh.h[lg * 4 + r][col + 16]      += acc01[r];
            sh.h[16 + lg * 4 + r][col]      += acc10[r];
            sh.h[16 + lg * 4 + r][col + 16] += acc11[r];
        }
    }
    __syncthreads();

    // FC2: 512 thr = 32 crops x 16 parts, 8 elems each; reduce within 16 lanes.
    int crop_l = tid >> 4, part = tid & 15;
    const float* hh = sh.h[crop_l];
    float s = 0.f;
    #pragma unroll
    for (int u = 0; u < 8; ++u)
        s += fmaxf(hh[part * 8 + u] + fc1_b[part * 8 + u], 0.f) * fc2_w[part * 8 + u];
    s += __shfl_down(s, 8, 16);
    s += __shfl_down(s, 4, 16);
    s += __shfl_down(s, 2, 16);
    s += __shfl_down(s, 1, 16);
    if (part == 0) {
        int m = m0 + crop_l;                 // < 9248 always
        int cls5 = m / 289, r2 = m - cls5 * 289;
        int c = r2 / 17, d = r2 - c * 17;
        int img = cls5 >> 4, o1 = (cls5 >> 3) & 1, o2 = (cls5 >> 2) & 1;
        int p1 = (cls5 >> 1) & 1, p2 = cls5 & 1;
        int i = 4 * c + 2 * p1 + o1;
        int j = 4 * d + 2 * p2 + o2;
        if (i <= 64 && j <= 64) {
            float q = 1.f / (1.f + expf(-(s + fc2_b[0])));
            out[img * (HIMG * HIMG) + (16 + i) * HIMG + (16 + j)] = q;
        }
    }
}

extern "C" void kernel_launch(void* const* d_in, const int* in_sizes, int n_in,
                              void* d_out, int out_size, void* d_ws, size_t ws_size,
                              hipStream_t stream) {
    const float* x     = (const float*)d_in[0];
    const float* w1    = (const float*)d_in[1];
    const float* b1    = (const float*)d_in[2];
    const float* w2    = (const float*)d_in[3];
    const float* b2    = (const float*)d_in[4];
    const float* fc1_w = (const float*)d_in[5];
    const float* fc1_b = (const float*)d_in[6];
    const float* fc2_w = (const float*)d_in[7];
    const float* fc2_b = (const float*)d_in[8];
    float* out = (float*)d_out;

    float* ws    = (float*)d_ws;
    float* pool1 = ws;                         // 270848 f32
    float* pool2 = pool1 + P1_SIZE;            // 495616 f32
    unsigned short* wBt = (unsigned short*)(pool2 + P2_SIZE);  // 147456 bf16

    k_front<<<784, 256, 0, stream>>>(x, w1, b1, pool1, fc1_w, wBt, out);
    k_convpool<<<512, 256, 0, stream>>>(pool1, w2, b2, pool2);
    k_fc<<<289, 512, 0, stream>>>(pool2, wBt, fc1_b, fc2_w, fc2_b, out);
}